// Round 14
// baseline (1827.629 us; speedup 1.0000x reference)
//
#include <hip/hip_runtime.h>
#include <hip/hip_bf16.h>

#define CC 64

typedef __attribute__((ext_vector_type(8))) short s16x8;
typedef __attribute__((ext_vector_type(4))) float f32x4;

__device__ __forceinline__ unsigned short f2b(float f) {   // f32 -> bf16 bits, RNE
    unsigned u = __float_as_uint(f);
    u += 0x7FFF + ((u >> 16) & 1);
    return (unsigned short)(u >> 16);
}
__device__ __forceinline__ unsigned fmono(float f) {       // order-preserving f32->u32
    unsigned u = __float_as_uint(f);
    return u ^ ((unsigned)((int)u >> 31) | 0x80000000u);
}

// ---- node kernel + fused dst-histogram (permuted channel layout) -------------------------
__global__ __launch_bounds__(256, 2) void node_proj_kernel(
    const float* __restrict__ x,
    const float* __restrict__ W_in, const float* __restrict__ b_in,
    const float* __restrict__ W_src, const float* __restrict__ W_dst,
    const float* __restrict__ W_lin, const float* __restrict__ aW1,
    float* __restrict__ AS, float* __restrict__ AD, float* __restrict__ xvv,
    const int* __restrict__ ei, unsigned* __restrict__ cnt, int N, int E)
{
    __shared__ float xt[64][68];
    __shared__ float ht[64][68];
    const int t = threadIdx.x, lane = t & 63, quad = t >> 6;
    const int n0 = blockIdx.x * 64;
    const int perm = (lane & 15) * 4 + (lane >> 4);
    float wreg[64];

    #pragma unroll 4
    for (int i = 0; i < 16; ++i) {
        int r = i*4 + quad, n = n0 + r;
        xt[r][lane] = (n < N) ? x[(size_t)n*CC + lane] : 0.f;
    }
    #pragma unroll
    for (int k4 = 0; k4 < 16; ++k4)
        *(float4*)&wreg[k4*4] = *(const float4*)&W_in[(size_t)lane*CC + k4*4];
    const float bi = b_in[lane];
    __syncthreads();

    #pragma unroll 2
    for (int i = 0; i < 16; ++i) {
        int r = i*4 + quad;
        float acc = bi;
        #pragma unroll
        for (int k4 = 0; k4 < 16; ++k4) {
            float4 xx = *(const float4*)&xt[r][k4*4];
            acc += xx.x*wreg[k4*4+0] + xx.y*wreg[k4*4+1]
                 + xx.z*wreg[k4*4+2] + xx.w*wreg[k4*4+3];
        }
        ht[r][lane] = fmaxf(acc, 0.f);
    }
    __syncthreads();

    const float* Wm[2] = {W_src, W_dst};
    float* Om[2] = {AS, AD};
    #pragma unroll
    for (int m = 0; m < 2; ++m) {
        #pragma unroll
        for (int k4 = 0; k4 < 16; ++k4)
            *(float4*)&wreg[k4*4] = *(const float4*)&Wm[m][(size_t)lane*CC + k4*4];
        #pragma unroll 2
        for (int i = 0; i < 16; ++i) {
            int r = i*4 + quad;
            float acc = 0.f;
            #pragma unroll
            for (int k4 = 0; k4 < 16; ++k4) {
                float4 xx = *(const float4*)&ht[r][k4*4];
                acc += xx.x*wreg[k4*4+0] + xx.y*wreg[k4*4+1]
                     + xx.z*wreg[k4*4+2] + xx.w*wreg[k4*4+3];
            }
            xt[r][lane] = acc;
        }
        __syncthreads();
        #pragma unroll
        for (int k = 0; k < 64; ++k) wreg[k] = aW1[(size_t)k*CC + lane];
        #pragma unroll 2
        for (int i = 0; i < 16; ++i) {
            int r = i*4 + quad, n = n0 + r;
            float acc = 0.f;
            #pragma unroll
            for (int k4 = 0; k4 < 16; ++k4) {
                float4 xx = *(const float4*)&xt[r][k4*4];
                acc += xx.x*wreg[k4*4+0] + xx.y*wreg[k4*4+1]
                     + xx.z*wreg[k4*4+2] + xx.w*wreg[k4*4+3];
            }
            if (n < N) Om[m][(size_t)n*CC + perm] = acc;
        }
        __syncthreads();
    }

    #pragma unroll
    for (int k4 = 0; k4 < 16; ++k4)
        *(float4*)&wreg[k4*4] = *(const float4*)&W_lin[(size_t)lane*CC + k4*4];
    #pragma unroll 2
    for (int i = 0; i < 16; ++i) {
        int r = i*4 + quad, n = n0 + r;
        float acc = 0.f;
        #pragma unroll
        for (int k4 = 0; k4 < 16; ++k4) {
            float4 xx = *(const float4*)&ht[r][k4*4];
            acc += xx.x*wreg[k4*4+0] + xx.y*wreg[k4*4+1]
                 + xx.z*wreg[k4*4+2] + xx.w*wreg[k4*4+3];
        }
        if (n < N) xvv[(size_t)n*CC + perm] = acc;
    }

    const int total = E + N;
    for (int e = blockIdx.x*256 + t; e < total; e += gridDim.x*256) {
        int d = (e < E) ? min(max(ei[(size_t)E + e], 0), N-1) : (e - E);
        atomicAdd(&cnt[d], 1u);
    }
}

// ---- exclusive scan (3 kernels) + scatter ------------------------------------------------
#define SCAN_T 256
__global__ __launch_bounds__(SCAN_T) void scan1_kernel(
    const unsigned* __restrict__ cnt, unsigned* __restrict__ chunk_off,
    unsigned* __restrict__ partials, int n)
{
    __shared__ unsigned sh[SCAN_T];
    const int t = threadIdx.x, b0 = blockIdx.x * (SCAN_T*4);
    unsigned v[4], s = 0;
    #pragma unroll
    for (int i = 0; i < 4; ++i) {
        int idx = b0 + t*4 + i;
        v[i] = (idx < n) ? cnt[idx] : 0u;
        s += v[i];
    }
    sh[t] = s; __syncthreads();
    for (int d = 1; d < SCAN_T; d <<= 1) {
        unsigned xv = (t >= d) ? sh[t-d] : 0u;
        __syncthreads();
        sh[t] += xv;
        __syncthreads();
    }
    unsigned run = (t > 0) ? sh[t-1] : 0u;
    #pragma unroll
    for (int i = 0; i < 4; ++i) {
        int idx = b0 + t*4 + i;
        if (idx < n) chunk_off[idx] = run;
        run += v[i];
    }
    if (t == SCAN_T-1) partials[blockIdx.x] = sh[SCAN_T-1];
}

__global__ __launch_bounds__(1024) void scan2_kernel(unsigned* __restrict__ partials, int nb)
{
    __shared__ unsigned sh[1024];
    const int t = threadIdx.x;
    sh[t] = (t < nb) ? partials[t] : 0u; __syncthreads();
    for (int d = 1; d < 1024; d <<= 1) {
        unsigned xv = (t >= d) ? sh[t-d] : 0u;
        __syncthreads();
        sh[t] += xv;
        __syncthreads();
    }
    if (t < nb) partials[t] = (t > 0) ? sh[t-1] : 0u;
}

__global__ __launch_bounds__(256) void scan3_kernel(
    const unsigned* __restrict__ chunk_off, const unsigned* __restrict__ partials,
    unsigned* __restrict__ cursor, int n)
{
    int i = blockIdx.x*256 + threadIdx.x;
    if (i < n) cursor[i] = chunk_off[i] + partials[i >> 10];
}

__global__ __launch_bounds__(256) void scatter_kernel(
    const int* __restrict__ ei, unsigned* __restrict__ cursor,
    int2* __restrict__ rec, int N, int E)
{
    const int total = E + N;
    for (int e = blockIdx.x*256 + threadIdx.x; e < total; e += gridDim.x*256) {
        int s, d;
        if (e < E) {
            s = min(max(ei[e], 0), N-1);
            d = min(max(ei[(size_t)E + e], 0), N-1);
        } else { s = d = e - E; }
        unsigned p = atomicAdd(&cursor[d], 1u);
        rec[p] = make_int2(s, d);
    }
}

// ---- edge kernel (r12 structure), templated for ablation ---------------------------------
// MODE 0: real.  MODE 1: atomics -> plain stores to dump (isolate atomic cost).
// MODE 2: gathers -> synthetic from indices; atomics hit scratch esum/outb (isolate gather).
template<int MODE>
__global__ __launch_bounds__(256, 3) void edge_mfma_kernel(
    const int2* __restrict__ rec, const float* __restrict__ pos,
    const float* __restrict__ AD, const float* __restrict__ AS, const float* __restrict__ xv,
    const float* __restrict__ pW1, const float* __restrict__ pb1,
    const float* __restrict__ pW2, const float* __restrict__ pb2,
    const float* __restrict__ aW1, const float* __restrict__ ab1,
    const float* __restrict__ aW2, const float* __restrict__ ab2,
    float* __restrict__ esum, unsigned* __restrict__ outb,
    float* __restrict__ dump,
    int N, int E)
{
    const int tid = threadIdx.x;
    const int lane = tid & 63;
    const int wid  = tid >> 6;
    const int lm = lane & 15;
    const int lg = lane >> 4;

    __shared__ __align__(16) unsigned short swt[3][64 * 72];
    __shared__ __align__(16) unsigned short tb[4][16 * 72];
    __shared__ unsigned spw[2][64];

    {
        const float* Wsrc[3] = {pW2, aW1, aW2};
        #pragma unroll
        for (int w = 0; w < 3; ++w)
            for (int idx = tid; idx < 4096; idx += 256) {
                int k = idx >> 6, o = idx & 63;
                swt[w][o*72 + k] = f2b(Wsrc[w][idx]);
            }
        if (tid < 64) {
            spw[0][tid] = (unsigned)f2b(pW1[tid])     | ((unsigned)f2b(pW1[64+tid]) << 16);
            spw[1][tid] = (unsigned)f2b(pW1[128+tid]) | ((unsigned)f2b(pb1[tid])    << 16);
        }
    }
    __syncthreads();

    float pb2v[4], ab1v[4], ab2v[4];
    #pragma unroll
    for (int tt = 0; tt < 4; ++tt) {
        pb2v[tt] = pb2[lm + 16*tt];
        ab1v[tt] = ab1[lm + 16*tt];
        ab2v[tt] = ab2[lm + 16*tt];
    }

    unsigned short* tbw = tb[wid];
    const int total = E + N;
    const int ntiles = (total + 15) >> 4;
    const int nwaves = gridDim.x * 4;
    const int tpw = (ntiles + nwaves - 1) / nwaves;
    const int gw = blockIdx.x * 4 + wid;
    const int t0 = gw * tpw;
    const int t1 = min(t0 + tpw, ntiles);
    if (t0 >= t1) return;

    int2 rp_n, rg_n0, rg_n1, rg_n2, rg_n3;
    {
        const int base = t0 << 4;
        int ep = base + lm; if (ep >= total) ep = total - 1;
        rp_n = rec[ep];
        int e0 = base + lg*4;
        rg_n0 = rec[min(e0+0, total-1)];
        rg_n1 = rec[min(e0+1, total-1)];
        rg_n2 = rec[min(e0+2, total-1)];
        rg_n3 = rec[min(e0+3, total-1)];
    }

    for (int tile = t0; tile < t1; ++tile) {
        const int base = tile << 4;
        const int2 rp = rp_n;
        int sg[4], dg[4];
        sg[0] = rg_n0.x; dg[0] = rg_n0.y;
        sg[1] = rg_n1.x; dg[1] = rg_n1.y;
        sg[2] = rg_n2.x; dg[2] = rg_n2.y;
        sg[3] = rg_n3.x; dg[3] = rg_n3.y;
        int actm = 0;
        #pragma unroll
        for (int r = 0; r < 4; ++r)
            if (base + lg*4 + r < total) actm |= (1 << r);

        float q0 = pos[(size_t)rp.y*3+0] - pos[(size_t)rp.x*3+0];
        float q1 = pos[(size_t)rp.y*3+1] - pos[(size_t)rp.x*3+1];
        float q2 = pos[(size_t)rp.y*3+2] - pos[(size_t)rp.x*3+2];

        // ---- gathers (or synthetic for MODE 2) ----
        float gd[4][4]; float4 xv4[4];
        #pragma unroll
        for (int r = 0; r < 4; ++r) {
            if (MODE == 2) {
                float fd = (float)dg[r] * 1e-6f, fs = (float)sg[r] * 1e-6f;
                gd[r][0] = fd - fs;       gd[r][1] = fd - fs * 0.5f;
                gd[r][2] = fd * 0.5f - fs; gd[r][3] = fd - fs * 0.25f;
                xv4[r] = make_float4(fs, fs*0.5f, fs*0.25f, fs*0.125f);
            } else {
                const float4 a4 = *(const float4*)&AD[(size_t)dg[r]*CC + lm*4];
                const float4 s4 = *(const float4*)&AS[(size_t)sg[r]*CC + lm*4];
                xv4[r] = *(const float4*)&xv[(size_t)sg[r]*CC + lm*4];
                gd[r][0] = a4.x - s4.x; gd[r][1] = a4.y - s4.y;
                gd[r][2] = a4.z - s4.z; gd[r][3] = a4.w - s4.w;
            }
        }

        if (tile + 1 < t1) {
            const int nb = (tile + 1) << 4;
            int ep = nb + lm; if (ep >= total) ep = total - 1;
            rp_n = rec[ep];
            int e0 = nb + lg*4;
            rg_n0 = rec[min(e0+0, total-1)];
            rg_n1 = rec[min(e0+1, total-1)];
            rg_n2 = rec[min(e0+2, total-1)];
            rg_n3 = rec[min(e0+3, total-1)];
        }

        // ---- p1 = relu(pdiff@pW1 + pb1) in A-frag layout ----
        s16x8 Alo, Ahi;
        #pragma unroll
        for (int j = 0; j < 16; ++j) {
            int k = lg*8 + (j & 7) + 32*(j >> 3);
            unsigned wa = ((volatile unsigned*)spw[0])[k];
            unsigned wb = ((volatile unsigned*)spw[1])[k];
            float w0 = __uint_as_float(wa << 16);
            float w1 = __uint_as_float(wa & 0xFFFF0000u);
            float w2 = __uint_as_float(wb << 16);
            float bb = __uint_as_float(wb & 0xFFFF0000u);
            float v = fmaxf(fmaf(q0, w0, fmaf(q1, w1, fmaf(q2, w2, bb))), 0.f);
            short b = (short)f2b(v);
            if (j < 8) Alo[j] = b; else Ahi[j-8] = b;
        }

        // ---- layer 1 ----
        f32x4 dlt[4];
        #pragma unroll
        for (int tt = 0; tt < 4; ++tt) {
            s16x8 b0 = *(const s16x8*)&swt[0][(lm + 16*tt)*72 + lg*8];
            s16x8 b1 = *(const s16x8*)&swt[0][(lm + 16*tt)*72 + 32 + lg*8];
            f32x4 z = {0.f, 0.f, 0.f, 0.f};
            z = __builtin_amdgcn_mfma_f32_16x16x32_bf16(Alo, b0, z, 0, 0, 0);
            z = __builtin_amdgcn_mfma_f32_16x16x32_bf16(Ahi, b1, z, 0, 0, 0);
            #pragma unroll
            for (int r = 0; r < 4; ++r) dlt[tt][r] = fmaxf(z[r] + pb2v[tt], 0.f);
        }

        // ---- transpose 1 ----
        #pragma unroll
        for (int tt = 0; tt < 4; ++tt)
            #pragma unroll
            for (int r = 0; r < 4; ++r)
                tbw[(lg*4+r)*72 + lm + 16*tt] = f2b(dlt[tt][r]);
        __builtin_amdgcn_wave_barrier();
        s16x8 Dlo = *(const s16x8*)&tbw[lm*72 + lg*8];
        s16x8 Dhi = *(const s16x8*)&tbw[lm*72 + 32 + lg*8];
        __builtin_amdgcn_wave_barrier();

        // ---- layer 2 ----
        #pragma unroll
        for (int tt = 0; tt < 4; ++tt) {
            s16x8 b0 = *(const s16x8*)&swt[1][(lm + 16*tt)*72 + lg*8];
            s16x8 b1 = *(const s16x8*)&swt[1][(lm + 16*tt)*72 + 32 + lg*8];
            f32x4 z = {0.f, 0.f, 0.f, 0.f};
            z = __builtin_amdgcn_mfma_f32_16x16x32_bf16(Dlo, b0, z, 0, 0, 0);
            z = __builtin_amdgcn_mfma_f32_16x16x32_bf16(Dhi, b1, z, 0, 0, 0);
            #pragma unroll
            for (int r = 0; r < 4; ++r) {
                float v = fmaxf(z[r] + gd[r][tt] + ab1v[tt], 0.f);
                tbw[(lg*4+r)*72 + lm + 16*tt] = f2b(v);
            }
        }
        __builtin_amdgcn_wave_barrier();
        s16x8 Hlo = *(const s16x8*)&tbw[lm*72 + lg*8];
        s16x8 Hhi = *(const s16x8*)&tbw[lm*72 + 32 + lg*8];
        __builtin_amdgcn_wave_barrier();

        // ---- layer 3 + aggregation ----
        #pragma unroll
        for (int tt = 0; tt < 4; ++tt) {
            s16x8 b0 = *(const s16x8*)&swt[2][(lm + 16*tt)*72 + lg*8];
            s16x8 b1 = *(const s16x8*)&swt[2][(lm + 16*tt)*72 + 32 + lg*8];
            f32x4 z = {0.f, 0.f, 0.f, 0.f};
            z = __builtin_amdgcn_mfma_f32_16x16x32_bf16(Hlo, b0, z, 0, 0, 0);
            z = __builtin_amdgcn_mfma_f32_16x16x32_bf16(Hhi, b1, z, 0, 0, 0);
            const int c = lm + 16*tt;
            int cur = -1; float s = 0.f, mx = 0.f, fl = 0.f;
            #pragma unroll
            for (int r = 0; r < 4; ++r) {
                if (!(actm & (1 << r))) continue;
                float a  = fmaxf(z[r] + ab2v[tt], 0.f);
                float ee = __expf(a);
                float m  = ee * (((const float*)&xv4[r])[tt] + dlt[tt][r]);
                if (dg[r] != cur) {
                    if (cur >= 0) {
                        if (MODE == 1) {
                            fl += s + mx;
                        } else {
                            size_t off = (size_t)cur*CC + c;
                            atomicAdd(&esum[off], s);
                            atomicMax(&outb[off], fmono(mx));
                        }
                    }
                    cur = dg[r]; s = 0.f; mx = -INFINITY;
                }
                s += ee; mx = fmaxf(mx, m);
            }
            if (cur >= 0) {
                if (MODE == 1) {
                    fl += s + mx;
                    dump[((size_t)gw*64 + lane)*4 + tt] = fl;
                } else {
                    size_t off = (size_t)cur*CC + c;
                    atomicAdd(&esum[off], s);
                    atomicMax(&outb[off], fmono(mx));
                }
            }
        }
    }
}

// ---- output kernel -----------------------------------------------------------------------
__global__ __launch_bounds__(256, 2) void out_kernel(
    const unsigned* outb_in,            // aliases out -- no restrict
    const float* __restrict__ esum,
    const float* __restrict__ W_out, const float* __restrict__ b_out,
    float* out, int N)
{
    __shared__ float vt[64][68];
    const int t = threadIdx.x, lane = t & 63, quad = t >> 6;
    const int n0 = blockIdx.x * 64;
    float wreg[64];
    #pragma unroll
    for (int k4 = 0; k4 < 16; ++k4)
        *(float4*)&wreg[k4*4] = *(const float4*)&W_out[(size_t)lane*CC + k4*4];
    #pragma unroll 4
    for (int i = 0; i < 16; ++i) {
        int r = i*4 + quad, n = n0 + r;
        float v = 0.f;
        if (n < N) {
            unsigned u = outb_in[(size_t)n*CC + lane];
            u = (u >> 31) ? (u ^ 0x80000000u) : ~u;   // inverse of fmono
            v = __uint_as_float(u) / esum[(size_t)n*CC + lane];
        }
        vt[r][lane] = v;
    }
    __syncthreads();
    const float bo = b_out[lane];
    #pragma unroll 2
    for (int i = 0; i < 16; ++i) {
        int r = i*4 + quad, n = n0 + r;
        if (n >= N) continue;
        float acc = bo;
        #pragma unroll
        for (int k4 = 0; k4 < 16; ++k4) {
            float4 xx = *(const float4*)&vt[r][k4*4];
            acc += xx.x*wreg[k4*4+0] + xx.y*wreg[k4*4+1]
                 + xx.z*wreg[k4*4+2] + xx.w*wreg[k4*4+3];
        }
        out[(size_t)n*CC + lane] = fmaxf(acc, 0.f);
    }
}

extern "C" void kernel_launch(void* const* d_in, const int* in_sizes, int n_in,
                              void* d_out, int out_size, void* d_ws, size_t ws_size,
                              hipStream_t stream)
{
    const float* x     = (const float*)d_in[0];
    const float* pos   = (const float*)d_in[1];
    const int*   ei    = (const int*)d_in[2];
    const float* W_in  = (const float*)d_in[3];
    const float* b_in  = (const float*)d_in[4];
    const float* W_out = (const float*)d_in[5];
    const float* b_out = (const float*)d_in[6];
    const float* W_lin = (const float*)d_in[7];
    const float* W_src = (const float*)d_in[8];
    const float* W_dst = (const float*)d_in[9];
    const float* pW1   = (const float*)d_in[10];
    const float* pb1   = (const float*)d_in[11];
    const float* pW2   = (const float*)d_in[12];
    const float* pb2   = (const float*)d_in[13];
    const float* aW1   = (const float*)d_in[14];
    const float* ab1   = (const float*)d_in[15];
    const float* aW2   = (const float*)d_in[16];
    const float* ab2   = (const float*)d_in[17];

    const int N = in_sizes[0] / CC;
    const int E = in_sizes[2] / 2;
    const int total = E + N;
    const size_t nc = (size_t)N * CC;

    char* wsb = (char*)d_ws;
    float* AS   = (float*)wsb;
    float* AD   = AS + nc;
    float* xvv  = AD + nc;
    float* esum = xvv + nc;
    unsigned* cnt       = (unsigned*)(esum + nc);
    unsigned* chunk_off = cnt + N;
    unsigned* cursor    = chunk_off + N;
    unsigned* partials  = cursor + N;          // 1024 entries
    size_t rec_off = ((4*nc + 3*(size_t)N + 1024) * 4 + 15) & ~(size_t)15;
    int2* rec = (int2*)(wsb + rec_off);
    size_t abl_off = (rec_off + (size_t)total*8 + 15) & ~(size_t)15;
    float*    esum2 = (float*)(wsb + abl_off);
    unsigned* outb2 = (unsigned*)(esum2 + nc);
    float*    dump  = (float*)(outb2 + nc);     // 8192 waves * 64 lanes * 4 floats = 8 MB
    size_t abl_need = abl_off + (2*nc + (size_t)8192*64*4) * 4;
    const bool do_ablate = (ws_size >= abl_need);

    unsigned* outb = (unsigned*)d_out;

    hipMemsetAsync(esum, 0, nc*sizeof(float), stream);
    hipMemsetAsync(outb, 0, nc*sizeof(float), stream);
    hipMemsetAsync(cnt, 0, (size_t)N*sizeof(unsigned), stream);

    const int nblk = (N + 63) / 64;
    node_proj_kernel<<<nblk, 256, 0, stream>>>(x, W_in, b_in, W_src, W_dst, W_lin, aW1,
                                               AS, AD, xvv, ei, cnt, N, E);
    const int nchunks = (N + 1023) / 1024;
    scan1_kernel<<<nchunks, SCAN_T, 0, stream>>>(cnt, chunk_off, partials, N);
    scan2_kernel<<<1, 1024, 0, stream>>>(partials, nchunks);
    scan3_kernel<<<(N + 255)/256, 256, 0, stream>>>(chunk_off, partials, cursor, N);
    scatter_kernel<<<2048, 256, 0, stream>>>(ei, cursor, rec, N, E);

    if (do_ablate) {
        // MODE 1: no atomics (plain stores to dump)
        edge_mfma_kernel<1><<<2048, 256, 0, stream>>>(rec, pos, AD, AS, xvv,
                                                      pW1, pb1, pW2, pb2, aW1, ab1, aW2, ab2,
                                                      esum2, outb2, dump, N, E);
        // MODE 2: no gathers (synthetic values, atomics to scratch)
        edge_mfma_kernel<2><<<2048, 256, 0, stream>>>(rec, pos, AD, AS, xvv,
                                                      pW1, pb1, pW2, pb2, aW1, ab1, aW2, ab2,
                                                      esum2, outb2, dump, N, E);
    }
    // MODE 0: real
    edge_mfma_kernel<0><<<2048, 256, 0, stream>>>(rec, pos, AD, AS, xvv,
                                                  pW1, pb1, pW2, pb2, aW1, ab1, aW2, ab2,
                                                  esum, outb, dump, N, E);
    out_kernel<<<nblk, 256, 0, stream>>>(outb, esum, W_out, b_out, (float*)d_out, N);
}

// Round 15
// 944.699 us; speedup vs baseline: 1.9346x; 1.9346x over previous
//
#include <hip/hip_runtime.h>
#include <hip/hip_bf16.h>

#define CC 64

typedef __attribute__((ext_vector_type(8))) short s16x8;
typedef __attribute__((ext_vector_type(4))) float f32x4;

__device__ __forceinline__ unsigned short f2b(float f) {   // f32 -> bf16 bits, RNE
    unsigned u = __float_as_uint(f);
    u += 0x7FFF + ((u >> 16) & 1);
    return (unsigned short)(u >> 16);
}
__device__ __forceinline__ float b2f(unsigned short b) {   // bf16 bits -> f32
    return __uint_as_float((unsigned)b << 16);
}
__device__ __forceinline__ unsigned fmono(float f) {       // order-preserving f32->u32
    unsigned u = __float_as_uint(f);
    return u ^ ((unsigned)((int)u >> 31) | 0x80000000u);
}

// ---- node kernel + fused dst-histogram (permuted channel layout) -------------------------
// AS/AD stored as bf16 (consumed at bf16 anyway); xv stays fp32.
__global__ __launch_bounds__(256, 2) void node_proj_kernel(
    const float* __restrict__ x,
    const float* __restrict__ W_in, const float* __restrict__ b_in,
    const float* __restrict__ W_src, const float* __restrict__ W_dst,
    const float* __restrict__ W_lin, const float* __restrict__ aW1,
    unsigned short* __restrict__ ASb, unsigned short* __restrict__ ADb,
    float* __restrict__ xvv,
    const int* __restrict__ ei, unsigned* __restrict__ cnt, int N, int E)
{
    __shared__ float xt[64][68];
    __shared__ float ht[64][68];
    const int t = threadIdx.x, lane = t & 63, quad = t >> 6;
    const int n0 = blockIdx.x * 64;
    const int perm = (lane & 15) * 4 + (lane >> 4);
    float wreg[64];

    #pragma unroll 4
    for (int i = 0; i < 16; ++i) {
        int r = i*4 + quad, n = n0 + r;
        xt[r][lane] = (n < N) ? x[(size_t)n*CC + lane] : 0.f;
    }
    #pragma unroll
    for (int k4 = 0; k4 < 16; ++k4)
        *(float4*)&wreg[k4*4] = *(const float4*)&W_in[(size_t)lane*CC + k4*4];
    const float bi = b_in[lane];
    __syncthreads();

    #pragma unroll 2
    for (int i = 0; i < 16; ++i) {
        int r = i*4 + quad;
        float acc = bi;
        #pragma unroll
        for (int k4 = 0; k4 < 16; ++k4) {
            float4 xx = *(const float4*)&xt[r][k4*4];
            acc += xx.x*wreg[k4*4+0] + xx.y*wreg[k4*4+1]
                 + xx.z*wreg[k4*4+2] + xx.w*wreg[k4*4+3];
        }
        ht[r][lane] = fmaxf(acc, 0.f);
    }
    __syncthreads();

    const float* Wm[2] = {W_src, W_dst};
    unsigned short* Om[2] = {ASb, ADb};
    #pragma unroll
    for (int m = 0; m < 2; ++m) {
        #pragma unroll
        for (int k4 = 0; k4 < 16; ++k4)
            *(float4*)&wreg[k4*4] = *(const float4*)&Wm[m][(size_t)lane*CC + k4*4];
        #pragma unroll 2
        for (int i = 0; i < 16; ++i) {
            int r = i*4 + quad;
            float acc = 0.f;
            #pragma unroll
            for (int k4 = 0; k4 < 16; ++k4) {
                float4 xx = *(const float4*)&ht[r][k4*4];
                acc += xx.x*wreg[k4*4+0] + xx.y*wreg[k4*4+1]
                     + xx.z*wreg[k4*4+2] + xx.w*wreg[k4*4+3];
            }
            xt[r][lane] = acc;
        }
        __syncthreads();
        #pragma unroll
        for (int k = 0; k < 64; ++k) wreg[k] = aW1[(size_t)k*CC + lane];
        #pragma unroll 2
        for (int i = 0; i < 16; ++i) {
            int r = i*4 + quad, n = n0 + r;
            float acc = 0.f;
            #pragma unroll
            for (int k4 = 0; k4 < 16; ++k4) {
                float4 xx = *(const float4*)&xt[r][k4*4];
                acc += xx.x*wreg[k4*4+0] + xx.y*wreg[k4*4+1]
                     + xx.z*wreg[k4*4+2] + xx.w*wreg[k4*4+3];
            }
            if (n < N) Om[m][(size_t)n*CC + perm] = f2b(acc);
        }
        __syncthreads();
    }

    #pragma unroll
    for (int k4 = 0; k4 < 16; ++k4)
        *(float4*)&wreg[k4*4] = *(const float4*)&W_lin[(size_t)lane*CC + k4*4];
    #pragma unroll 2
    for (int i = 0; i < 16; ++i) {
        int r = i*4 + quad, n = n0 + r;
        float acc = 0.f;
        #pragma unroll
        for (int k4 = 0; k4 < 16; ++k4) {
            float4 xx = *(const float4*)&ht[r][k4*4];
            acc += xx.x*wreg[k4*4+0] + xx.y*wreg[k4*4+1]
                 + xx.z*wreg[k4*4+2] + xx.w*wreg[k4*4+3];
        }
        if (n < N) xvv[(size_t)n*CC + perm] = acc;
    }

    const int total = E + N;
    for (int e = blockIdx.x*256 + t; e < total; e += gridDim.x*256) {
        int d = (e < E) ? min(max(ei[(size_t)E + e], 0), N-1) : (e - E);
        atomicAdd(&cnt[d], 1u);
    }
}

// ---- exclusive scan (3 kernels) + scatter ------------------------------------------------
#define SCAN_T 256
__global__ __launch_bounds__(SCAN_T) void scan1_kernel(
    const unsigned* __restrict__ cnt, unsigned* __restrict__ chunk_off,
    unsigned* __restrict__ partials, int n)
{
    __shared__ unsigned sh[SCAN_T];
    const int t = threadIdx.x, b0 = blockIdx.x * (SCAN_T*4);
    unsigned v[4], s = 0;
    #pragma unroll
    for (int i = 0; i < 4; ++i) {
        int idx = b0 + t*4 + i;
        v[i] = (idx < n) ? cnt[idx] : 0u;
        s += v[i];
    }
    sh[t] = s; __syncthreads();
    for (int d = 1; d < SCAN_T; d <<= 1) {
        unsigned xv = (t >= d) ? sh[t-d] : 0u;
        __syncthreads();
        sh[t] += xv;
        __syncthreads();
    }
    unsigned run = (t > 0) ? sh[t-1] : 0u;
    #pragma unroll
    for (int i = 0; i < 4; ++i) {
        int idx = b0 + t*4 + i;
        if (idx < n) chunk_off[idx] = run;
        run += v[i];
    }
    if (t == SCAN_T-1) partials[blockIdx.x] = sh[SCAN_T-1];
}

__global__ __launch_bounds__(1024) void scan2_kernel(unsigned* __restrict__ partials, int nb)
{
    __shared__ unsigned sh[1024];
    const int t = threadIdx.x;
    sh[t] = (t < nb) ? partials[t] : 0u; __syncthreads();
    for (int d = 1; d < 1024; d <<= 1) {
        unsigned xv = (t >= d) ? sh[t-d] : 0u;
        __syncthreads();
        sh[t] += xv;
        __syncthreads();
    }
    if (t < nb) partials[t] = (t > 0) ? sh[t-1] : 0u;
}

__global__ __launch_bounds__(256) void scan3_kernel(
    const unsigned* __restrict__ chunk_off, const unsigned* __restrict__ partials,
    unsigned* __restrict__ cursor, int n)
{
    int i = blockIdx.x*256 + threadIdx.x;
    if (i < n) cursor[i] = chunk_off[i] + partials[i >> 10];
}

__global__ __launch_bounds__(256) void scatter_kernel(
    const int* __restrict__ ei, unsigned* __restrict__ cursor,
    int2* __restrict__ rec, int N, int E)
{
    const int total = E + N;
    for (int e = blockIdx.x*256 + threadIdx.x; e < total; e += gridDim.x*256) {
        int s, d;
        if (e < E) {
            s = min(max(ei[e], 0), N-1);
            d = min(max(ei[(size_t)E + e], 0), N-1);
        } else { s = d = e - E; }
        unsigned p = atomicAdd(&cursor[d], 1u);
        rec[p] = make_int2(s, d);
    }
}

// ---- edge kernel: bf16 AS/AD gathers + cross-tile run-carried atomics --------------------
__global__ __launch_bounds__(256, 3) void edge_mfma_kernel(
    const int2* __restrict__ rec, const float* __restrict__ pos,
    const unsigned short* __restrict__ ADb, const unsigned short* __restrict__ ASb,
    const float* __restrict__ xv,
    const float* __restrict__ pW1, const float* __restrict__ pb1,
    const float* __restrict__ pW2, const float* __restrict__ pb2,
    const float* __restrict__ aW1, const float* __restrict__ ab1,
    const float* __restrict__ aW2, const float* __restrict__ ab2,
    float* __restrict__ esum, unsigned* __restrict__ outb,
    int N, int E)
{
    const int tid = threadIdx.x;
    const int lane = tid & 63;
    const int wid  = tid >> 6;
    const int lm = lane & 15;
    const int lg = lane >> 4;

    __shared__ __align__(16) unsigned short swt[3][64 * 72];
    __shared__ __align__(16) unsigned short tb[4][16 * 72];
    __shared__ unsigned spw[2][64];

    {
        const float* Wsrc[3] = {pW2, aW1, aW2};
        #pragma unroll
        for (int w = 0; w < 3; ++w)
            for (int idx = tid; idx < 4096; idx += 256) {
                int k = idx >> 6, o = idx & 63;
                swt[w][o*72 + k] = f2b(Wsrc[w][idx]);
            }
        if (tid < 64) {
            spw[0][tid] = (unsigned)f2b(pW1[tid])     | ((unsigned)f2b(pW1[64+tid]) << 16);
            spw[1][tid] = (unsigned)f2b(pW1[128+tid]) | ((unsigned)f2b(pb1[tid])    << 16);
        }
    }
    __syncthreads();

    float pb2v[4], ab1v[4], ab2v[4];
    #pragma unroll
    for (int tt = 0; tt < 4; ++tt) {
        pb2v[tt] = pb2[lm + 16*tt];
        ab1v[tt] = ab1[lm + 16*tt];
        ab2v[tt] = ab2[lm + 16*tt];
    }

    unsigned short* tbw = tb[wid];
    const int total = E + N;
    const int ntiles = (total + 15) >> 4;
    const int nwaves = gridDim.x * 4;
    const int tpw = (ntiles + nwaves - 1) / nwaves;
    const int gw = blockIdx.x * 4 + wid;
    const int t0 = gw * tpw;
    const int t1 = min(t0 + tpw, ntiles);
    if (t0 >= t1) return;

    // cross-tile run-carried aggregation state (dst non-decreasing over lane's sequence)
    int   curD[4] = {-1, -1, -1, -1};
    float sA[4]   = {0.f, 0.f, 0.f, 0.f};
    float mxA[4]  = {-INFINITY, -INFINITY, -INFINITY, -INFINITY};

    int2 rp_n, rg_n0, rg_n1, rg_n2, rg_n3;
    {
        const int base = t0 << 4;
        int ep = base + lm; if (ep >= total) ep = total - 1;
        rp_n = rec[ep];
        int e0 = base + lg*4;
        rg_n0 = rec[min(e0+0, total-1)];
        rg_n1 = rec[min(e0+1, total-1)];
        rg_n2 = rec[min(e0+2, total-1)];
        rg_n3 = rec[min(e0+3, total-1)];
    }

    for (int tile = t0; tile < t1; ++tile) {
        const int base = tile << 4;
        const int2 rp = rp_n;
        int sg[4], dg[4];
        sg[0] = rg_n0.x; dg[0] = rg_n0.y;
        sg[1] = rg_n1.x; dg[1] = rg_n1.y;
        sg[2] = rg_n2.x; dg[2] = rg_n2.y;
        sg[3] = rg_n3.x; dg[3] = rg_n3.y;
        int actm = 0;
        #pragma unroll
        for (int r = 0; r < 4; ++r)
            if (base + lg*4 + r < total) actm |= (1 << r);

        float q0 = pos[(size_t)rp.y*3+0] - pos[(size_t)rp.x*3+0];
        float q1 = pos[(size_t)rp.y*3+1] - pos[(size_t)rp.x*3+1];
        float q2 = pos[(size_t)rp.y*3+2] - pos[(size_t)rp.x*3+2];

        // ---- gathers: bf16 ushort4 for AD/AS, float4 for xv ----
        float gd[4][4]; float4 xv4[4];
        #pragma unroll
        for (int r = 0; r < 4; ++r) {
            const ushort4 a4 = *(const ushort4*)&ADb[(size_t)dg[r]*CC + lm*4];
            const ushort4 s4 = *(const ushort4*)&ASb[(size_t)sg[r]*CC + lm*4];
            xv4[r] = *(const float4*)&xv[(size_t)sg[r]*CC + lm*4];
            gd[r][0] = b2f(a4.x) - b2f(s4.x);
            gd[r][1] = b2f(a4.y) - b2f(s4.y);
            gd[r][2] = b2f(a4.z) - b2f(s4.z);
            gd[r][3] = b2f(a4.w) - b2f(s4.w);
        }

        if (tile + 1 < t1) {
            const int nb = (tile + 1) << 4;
            int ep = nb + lm; if (ep >= total) ep = total - 1;
            rp_n = rec[ep];
            int e0 = nb + lg*4;
            rg_n0 = rec[min(e0+0, total-1)];
            rg_n1 = rec[min(e0+1, total-1)];
            rg_n2 = rec[min(e0+2, total-1)];
            rg_n3 = rec[min(e0+3, total-1)];
        }

        // ---- p1 = relu(pdiff@pW1 + pb1) in A-frag layout ----
        s16x8 Alo, Ahi;
        #pragma unroll
        for (int j = 0; j < 16; ++j) {
            int k = lg*8 + (j & 7) + 32*(j >> 3);
            unsigned wa = ((volatile unsigned*)spw[0])[k];
            unsigned wb = ((volatile unsigned*)spw[1])[k];
            float w0 = __uint_as_float(wa << 16);
            float w1 = __uint_as_float(wa & 0xFFFF0000u);
            float w2 = __uint_as_float(wb << 16);
            float bb = __uint_as_float(wb & 0xFFFF0000u);
            float v = fmaxf(fmaf(q0, w0, fmaf(q1, w1, fmaf(q2, w2, bb))), 0.f);
            short b = (short)f2b(v);
            if (j < 8) Alo[j] = b; else Ahi[j-8] = b;
        }

        // ---- layer 1: delta = relu(p1 @ pW2 + pb2) ----
        f32x4 dlt[4];
        #pragma unroll
        for (int tt = 0; tt < 4; ++tt) {
            s16x8 b0 = *(const s16x8*)&swt[0][(lm + 16*tt)*72 + lg*8];
            s16x8 b1 = *(const s16x8*)&swt[0][(lm + 16*tt)*72 + 32 + lg*8];
            f32x4 z = {0.f, 0.f, 0.f, 0.f};
            z = __builtin_amdgcn_mfma_f32_16x16x32_bf16(Alo, b0, z, 0, 0, 0);
            z = __builtin_amdgcn_mfma_f32_16x16x32_bf16(Ahi, b1, z, 0, 0, 0);
            #pragma unroll
            for (int r = 0; r < 4; ++r) dlt[tt][r] = fmaxf(z[r] + pb2v[tt], 0.f);
        }

        // ---- transpose 1 ----
        #pragma unroll
        for (int tt = 0; tt < 4; ++tt)
            #pragma unroll
            for (int r = 0; r < 4; ++r)
                tbw[(lg*4+r)*72 + lm + 16*tt] = f2b(dlt[tt][r]);
        __builtin_amdgcn_wave_barrier();
        s16x8 Dlo = *(const s16x8*)&tbw[lm*72 + lg*8];
        s16x8 Dhi = *(const s16x8*)&tbw[lm*72 + 32 + lg*8];
        __builtin_amdgcn_wave_barrier();

        // ---- layer 2: h1 = relu(gd + delta@aW1 + ab1) -> transpose 2 ----
        #pragma unroll
        for (int tt = 0; tt < 4; ++tt) {
            s16x8 b0 = *(const s16x8*)&swt[1][(lm + 16*tt)*72 + lg*8];
            s16x8 b1 = *(const s16x8*)&swt[1][(lm + 16*tt)*72 + 32 + lg*8];
            f32x4 z = {0.f, 0.f, 0.f, 0.f};
            z = __builtin_amdgcn_mfma_f32_16x16x32_bf16(Dlo, b0, z, 0, 0, 0);
            z = __builtin_amdgcn_mfma_f32_16x16x32_bf16(Dhi, b1, z, 0, 0, 0);
            #pragma unroll
            for (int r = 0; r < 4; ++r) {
                float v = fmaxf(z[r] + gd[r][tt] + ab1v[tt], 0.f);
                tbw[(lg*4+r)*72 + lm + 16*tt] = f2b(v);
            }
        }
        __builtin_amdgcn_wave_barrier();
        s16x8 Hlo = *(const s16x8*)&tbw[lm*72 + lg*8];
        s16x8 Hhi = *(const s16x8*)&tbw[lm*72 + 32 + lg*8];
        __builtin_amdgcn_wave_barrier();

        // ---- layer 3 + run-carried atomics ----
        #pragma unroll
        for (int tt = 0; tt < 4; ++tt) {
            s16x8 b0 = *(const s16x8*)&swt[2][(lm + 16*tt)*72 + lg*8];
            s16x8 b1 = *(const s16x8*)&swt[2][(lm + 16*tt)*72 + 32 + lg*8];
            f32x4 z = {0.f, 0.f, 0.f, 0.f};
            z = __builtin_amdgcn_mfma_f32_16x16x32_bf16(Hlo, b0, z, 0, 0, 0);
            z = __builtin_amdgcn_mfma_f32_16x16x32_bf16(Hhi, b1, z, 0, 0, 0);
            const int c = lm + 16*tt;
            #pragma unroll
            for (int r = 0; r < 4; ++r) {
                if (!(actm & (1 << r))) continue;
                float a  = fmaxf(z[r] + ab2v[tt], 0.f);
                float ee = __expf(a);
                float m  = ee * (((const float*)&xv4[r])[tt] + dlt[tt][r]);
                if (dg[r] != curD[tt]) {
                    if (curD[tt] >= 0) {
                        size_t off = (size_t)curD[tt]*CC + c;
                        atomicAdd(&esum[off], sA[tt]);
                        atomicMax(&outb[off], fmono(mxA[tt]));
                    }
                    curD[tt] = dg[r]; sA[tt] = 0.f; mxA[tt] = -INFINITY;
                }
                sA[tt] += ee; mxA[tt] = fmaxf(mxA[tt], m);
            }
        }
    }

    // ---- epilogue: flush carried runs ----
    #pragma unroll
    for (int tt = 0; tt < 4; ++tt) {
        if (curD[tt] >= 0) {
            size_t off = (size_t)curD[tt]*CC + lm + 16*tt;
            atomicAdd(&esum[off], sA[tt]);
            atomicMax(&outb[off], fmono(mxA[tt]));
        }
    }
}

// ---- output kernel -----------------------------------------------------------------------
__global__ __launch_bounds__(256, 2) void out_kernel(
    const unsigned* outb_in,            // aliases out -- no restrict
    const float* __restrict__ esum,
    const float* __restrict__ W_out, const float* __restrict__ b_out,
    float* out, int N)
{
    __shared__ float vt[64][68];
    const int t = threadIdx.x, lane = t & 63, quad = t >> 6;
    const int n0 = blockIdx.x * 64;
    float wreg[64];
    #pragma unroll
    for (int k4 = 0; k4 < 16; ++k4)
        *(float4*)&wreg[k4*4] = *(const float4*)&W_out[(size_t)lane*CC + k4*4];
    #pragma unroll 4
    for (int i = 0; i < 16; ++i) {
        int r = i*4 + quad, n = n0 + r;
        float v = 0.f;
        if (n < N) {
            unsigned u = outb_in[(size_t)n*CC + lane];
            u = (u >> 31) ? (u ^ 0x80000000u) : ~u;   // inverse of fmono
            v = __uint_as_float(u) / esum[(size_t)n*CC + lane];
        }
        vt[r][lane] = v;
    }
    __syncthreads();
    const float bo = b_out[lane];
    #pragma unroll 2
    for (int i = 0; i < 16; ++i) {
        int r = i*4 + quad, n = n0 + r;
        if (n >= N) continue;
        float acc = bo;
        #pragma unroll
        for (int k4 = 0; k4 < 16; ++k4) {
            float4 xx = *(const float4*)&vt[r][k4*4];
            acc += xx.x*wreg[k4*4+0] + xx.y*wreg[k4*4+1]
                 + xx.z*wreg[k4*4+2] + xx.w*wreg[k4*4+3];
        }
        out[(size_t)n*CC + lane] = fmaxf(acc, 0.f);
    }
}

extern "C" void kernel_launch(void* const* d_in, const int* in_sizes, int n_in,
                              void* d_out, int out_size, void* d_ws, size_t ws_size,
                              hipStream_t stream)
{
    const float* x     = (const float*)d_in[0];
    const float* pos   = (const float*)d_in[1];
    const int*   ei    = (const int*)d_in[2];
    const float* W_in  = (const float*)d_in[3];
    const float* b_in  = (const float*)d_in[4];
    const float* W_out = (const float*)d_in[5];
    const float* b_out = (const float*)d_in[6];
    const float* W_lin = (const float*)d_in[7];
    const float* W_src = (const float*)d_in[8];
    const float* W_dst = (const float*)d_in[9];
    const float* pW1   = (const float*)d_in[10];
    const float* pb1   = (const float*)d_in[11];
    const float* pW2   = (const float*)d_in[12];
    const float* pb2   = (const float*)d_in[13];
    const float* aW1   = (const float*)d_in[14];
    const float* ab1   = (const float*)d_in[15];
    const float* aW2   = (const float*)d_in[16];
    const float* ab2   = (const float*)d_in[17];

    const int N = in_sizes[0] / CC;
    const int E = in_sizes[2] / 2;
    const int total = E + N;
    const size_t nc = (size_t)N * CC;

    char* wsb = (char*)d_ws;
    unsigned short* ASb = (unsigned short*)wsb;        // nc * 2B
    unsigned short* ADb = ASb + nc;                    // nc * 2B
    float* xvv  = (float*)(ADb + nc);                  // nc * 4B
    float* esum = xvv + nc;                            // nc * 4B
    unsigned* cnt       = (unsigned*)(esum + nc);
    unsigned* chunk_off = cnt + N;
    unsigned* cursor    = chunk_off + N;
    unsigned* partials  = cursor + N;                  // 1024 entries
    size_t rec_off = ((size_t)((char*)(partials + 1024) - wsb) + 15) & ~(size_t)15;
    int2* rec = (int2*)(wsb + rec_off);
    unsigned* outb = (unsigned*)d_out;

    hipMemsetAsync(esum, 0, nc*sizeof(float), stream);
    hipMemsetAsync(outb, 0, nc*sizeof(float), stream);
    hipMemsetAsync(cnt, 0, (size_t)N*sizeof(unsigned), stream);

    const int nblk = (N + 63) / 64;
    node_proj_kernel<<<nblk, 256, 0, stream>>>(x, W_in, b_in, W_src, W_dst, W_lin, aW1,
                                               ASb, ADb, xvv, ei, cnt, N, E);
    const int nchunks = (N + 1023) / 1024;
    scan1_kernel<<<nchunks, SCAN_T, 0, stream>>>(cnt, chunk_off, partials, N);
    scan2_kernel<<<1, 1024, 0, stream>>>(partials, nchunks);
    scan3_kernel<<<(N + 255)/256, 256, 0, stream>>>(chunk_off, partials, cursor, N);
    scatter_kernel<<<2048, 256, 0, stream>>>(ei, cursor, rec, N, E);
    edge_mfma_kernel<<<2048, 256, 0, stream>>>(rec, pos, ADb, ASb, xvv,
                                               pW1, pb1, pW2, pb2, aW1, ab1, aW2, ab2,
                                               esum, outb, N, E);
    out_kernel<<<nblk, 256, 0, stream>>>(outb, esum, W_out, b_out, (float*)d_out, N);
}

// Round 16
// 659.573 us; speedup vs baseline: 2.7709x; 1.4323x over previous
//
#include <hip/hip_runtime.h>
#include <hip/hip_bf16.h>

#define CC 64

typedef __attribute__((ext_vector_type(8))) short s16x8;
typedef __attribute__((ext_vector_type(4))) float f32x4;

__device__ __forceinline__ unsigned short f2b(float f) {   // f32 -> bf16 bits, RNE
    unsigned u = __float_as_uint(f);
    u += 0x7FFF + ((u >> 16) & 1);
    return (unsigned short)(u >> 16);
}
__device__ __forceinline__ float b2f(unsigned short b) {   // bf16 bits -> f32
    return __uint_as_float((unsigned)b << 16);
}
__device__ __forceinline__ unsigned fmono(float f) {       // order-preserving f32->u32
    unsigned u = __float_as_uint(f);
    return u ^ ((unsigned)((int)u >> 31) | 0x80000000u);
}

// ---- node kernel + fused dst-histogram (permuted channel layout) -------------------------
// AS/AD/xv all stored as bf16 in permuted layout (channel c -> column (c&15)*4 + (c>>4)).
__global__ __launch_bounds__(256, 2) void node_proj_kernel(
    const float* __restrict__ x,
    const float* __restrict__ W_in, const float* __restrict__ b_in,
    const float* __restrict__ W_src, const float* __restrict__ W_dst,
    const float* __restrict__ W_lin, const float* __restrict__ aW1,
    unsigned short* __restrict__ ASb, unsigned short* __restrict__ ADb,
    unsigned short* __restrict__ xvb,
    const int* __restrict__ ei, unsigned* __restrict__ cnt, int N, int E)
{
    __shared__ float xt[64][68];
    __shared__ float ht[64][68];
    const int t = threadIdx.x, lane = t & 63, quad = t >> 6;
    const int n0 = blockIdx.x * 64;
    const int perm = (lane & 15) * 4 + (lane >> 4);
    float wreg[64];

    #pragma unroll 4
    for (int i = 0; i < 16; ++i) {
        int r = i*4 + quad, n = n0 + r;
        xt[r][lane] = (n < N) ? x[(size_t)n*CC + lane] : 0.f;
    }
    #pragma unroll
    for (int k4 = 0; k4 < 16; ++k4)
        *(float4*)&wreg[k4*4] = *(const float4*)&W_in[(size_t)lane*CC + k4*4];
    const float bi = b_in[lane];
    __syncthreads();

    #pragma unroll 2
    for (int i = 0; i < 16; ++i) {
        int r = i*4 + quad;
        float acc = bi;
        #pragma unroll
        for (int k4 = 0; k4 < 16; ++k4) {
            float4 xx = *(const float4*)&xt[r][k4*4];
            acc += xx.x*wreg[k4*4+0] + xx.y*wreg[k4*4+1]
                 + xx.z*wreg[k4*4+2] + xx.w*wreg[k4*4+3];
        }
        ht[r][lane] = fmaxf(acc, 0.f);
    }
    __syncthreads();

    const float* Wm[2] = {W_src, W_dst};
    unsigned short* Om[2] = {ASb, ADb};
    #pragma unroll
    for (int m = 0; m < 2; ++m) {
        #pragma unroll
        for (int k4 = 0; k4 < 16; ++k4)
            *(float4*)&wreg[k4*4] = *(const float4*)&Wm[m][(size_t)lane*CC + k4*4];
        #pragma unroll 2
        for (int i = 0; i < 16; ++i) {
            int r = i*4 + quad;
            float acc = 0.f;
            #pragma unroll
            for (int k4 = 0; k4 < 16; ++k4) {
                float4 xx = *(const float4*)&ht[r][k4*4];
                acc += xx.x*wreg[k4*4+0] + xx.y*wreg[k4*4+1]
                     + xx.z*wreg[k4*4+2] + xx.w*wreg[k4*4+3];
            }
            xt[r][lane] = acc;
        }
        __syncthreads();
        #pragma unroll
        for (int k = 0; k < 64; ++k) wreg[k] = aW1[(size_t)k*CC + lane];
        #pragma unroll 2
        for (int i = 0; i < 16; ++i) {
            int r = i*4 + quad, n = n0 + r;
            float acc = 0.f;
            #pragma unroll
            for (int k4 = 0; k4 < 16; ++k4) {
                float4 xx = *(const float4*)&xt[r][k4*4];
                acc += xx.x*wreg[k4*4+0] + xx.y*wreg[k4*4+1]
                     + xx.z*wreg[k4*4+2] + xx.w*wreg[k4*4+3];
            }
            if (n < N) Om[m][(size_t)n*CC + perm] = f2b(acc);
        }
        __syncthreads();
    }

    #pragma unroll
    for (int k4 = 0; k4 < 16; ++k4)
        *(float4*)&wreg[k4*4] = *(const float4*)&W_lin[(size_t)lane*CC + k4*4];
    #pragma unroll 2
    for (int i = 0; i < 16; ++i) {
        int r = i*4 + quad, n = n0 + r;
        float acc = 0.f;
        #pragma unroll
        for (int k4 = 0; k4 < 16; ++k4) {
            float4 xx = *(const float4*)&ht[r][k4*4];
            acc += xx.x*wreg[k4*4+0] + xx.y*wreg[k4*4+1]
                 + xx.z*wreg[k4*4+2] + xx.w*wreg[k4*4+3];
        }
        if (n < N) xvb[(size_t)n*CC + perm] = f2b(acc);
    }

    const int total = E + N;
    for (int e = blockIdx.x*256 + t; e < total; e += gridDim.x*256) {
        int d = (e < E) ? min(max(ei[(size_t)E + e], 0), N-1) : (e - E);
        atomicAdd(&cnt[d], 1u);
    }
}

// ---- exclusive scan (3 kernels) + scatter ------------------------------------------------
#define SCAN_T 256
__global__ __launch_bounds__(SCAN_T) void scan1_kernel(
    const unsigned* __restrict__ cnt, unsigned* __restrict__ chunk_off,
    unsigned* __restrict__ partials, int n)
{
    __shared__ unsigned sh[SCAN_T];
    const int t = threadIdx.x, b0 = blockIdx.x * (SCAN_T*4);
    unsigned v[4], s = 0;
    #pragma unroll
    for (int i = 0; i < 4; ++i) {
        int idx = b0 + t*4 + i;
        v[i] = (idx < n) ? cnt[idx] : 0u;
        s += v[i];
    }
    sh[t] = s; __syncthreads();
    for (int d = 1; d < SCAN_T; d <<= 1) {
        unsigned xv = (t >= d) ? sh[t-d] : 0u;
        __syncthreads();
        sh[t] += xv;
        __syncthreads();
    }
    unsigned run = (t > 0) ? sh[t-1] : 0u;
    #pragma unroll
    for (int i = 0; i < 4; ++i) {
        int idx = b0 + t*4 + i;
        if (idx < n) chunk_off[idx] = run;
        run += v[i];
    }
    if (t == SCAN_T-1) partials[blockIdx.x] = sh[SCAN_T-1];
}

__global__ __launch_bounds__(1024) void scan2_kernel(unsigned* __restrict__ partials, int nb)
{
    __shared__ unsigned sh[1024];
    const int t = threadIdx.x;
    sh[t] = (t < nb) ? partials[t] : 0u; __syncthreads();
    for (int d = 1; d < 1024; d <<= 1) {
        unsigned xv = (t >= d) ? sh[t-d] : 0u;
        __syncthreads();
        sh[t] += xv;
        __syncthreads();
    }
    if (t < nb) partials[t] = (t > 0) ? sh[t-1] : 0u;
}

__global__ __launch_bounds__(256) void scan3_kernel(
    const unsigned* __restrict__ chunk_off, const unsigned* __restrict__ partials,
    unsigned* __restrict__ cursor, int n)
{
    int i = blockIdx.x*256 + threadIdx.x;
    if (i < n) cursor[i] = chunk_off[i] + partials[i >> 10];
}

__global__ __launch_bounds__(256) void scatter_kernel(
    const int* __restrict__ ei, unsigned* __restrict__ cursor,
    int2* __restrict__ rec, int N, int E)
{
    const int total = E + N;
    for (int e = blockIdx.x*256 + threadIdx.x; e < total; e += gridDim.x*256) {
        int s, d;
        if (e < E) {
            s = min(max(ei[e], 0), N-1);
            d = min(max(ei[(size_t)E + e], 0), N-1);
        } else { s = d = e - E; }
        unsigned p = atomicAdd(&cursor[d], 1u);
        rec[p] = make_int2(s, d);
    }
}

// ---- edge kernel: contiguous per-lg quarters; interior runs -> PLAIN stores --------------
// Each wave owns a contiguous sorted-edge range; each lg group owns a contiguous quarter.
// A dst run strictly inside a quarter has exactly one writer -> plain store. Only the
// first flush and the epilogue flush of each quarter may be shared -> atomics.
__global__ __launch_bounds__(256, 3) void edge_mfma_kernel(
    const int2* __restrict__ rec, const float* __restrict__ pos,
    const unsigned short* __restrict__ ADb, const unsigned short* __restrict__ ASb,
    const unsigned short* __restrict__ xvb,
    const float* __restrict__ pW1, const float* __restrict__ pb1,
    const float* __restrict__ pW2, const float* __restrict__ pb2,
    const float* __restrict__ aW1, const float* __restrict__ ab1,
    const float* __restrict__ aW2, const float* __restrict__ ab2,
    float* __restrict__ esum, unsigned* __restrict__ outb,
    int N, int E)
{
    const int tid = threadIdx.x;
    const int lane = tid & 63;
    const int wid  = tid >> 6;
    const int lm = lane & 15;
    const int lg = lane >> 4;

    __shared__ __align__(16) unsigned short swt[3][64 * 72];
    __shared__ __align__(16) unsigned short tb[4][16 * 72];
    __shared__ unsigned spw[2][64];

    {
        const float* Wsrc[3] = {pW2, aW1, aW2};
        #pragma unroll
        for (int w = 0; w < 3; ++w)
            for (int idx = tid; idx < 4096; idx += 256) {
                int k = idx >> 6, o = idx & 63;
                swt[w][o*72 + k] = f2b(Wsrc[w][idx]);
            }
        if (tid < 64) {
            spw[0][tid] = (unsigned)f2b(pW1[tid])     | ((unsigned)f2b(pW1[64+tid]) << 16);
            spw[1][tid] = (unsigned)f2b(pW1[128+tid]) | ((unsigned)f2b(pb1[tid])    << 16);
        }
    }
    __syncthreads();

    float pb2v[4], ab1v[4], ab2v[4];
    #pragma unroll
    for (int tt = 0; tt < 4; ++tt) {
        pb2v[tt] = pb2[lm + 16*tt];
        ab1v[tt] = ab1[lm + 16*tt];
        ab2v[tt] = ab2[lm + 16*tt];
    }

    unsigned short* tbw = tb[wid];
    const int total = E + N;
    const int ntiles = (total + 15) >> 4;
    const int nwaves = gridDim.x * 4;
    const int tpw = (ntiles + nwaves - 1) / nwaves;
    const int gw = blockIdx.x * 4 + wid;
    const int t0 = min(gw * tpw, ntiles);
    const int t1 = min(t0 + tpw, ntiles);
    if (t0 >= t1) return;
    const int nstep = t1 - t0;
    const int qlen  = 4 * nstep;             // edges per lg quarter
    const int rbase = t0 << 4;               // range start (edge index)
    const int pq = rbase + (lm >> 2)*qlen + (lm & 3);   // p-path base (+ step*4)
    const int gq = rbase + lg*qlen;                     // gather base  (+ step*4 + r)

    // run-carried aggregation state (dst uniform across tt)
    int   curD = -1;
    bool  firstF = true;
    float sA[4]  = {0.f, 0.f, 0.f, 0.f};
    float mxA[4] = {-INFINITY, -INFINITY, -INFINITY, -INFINITY};

    int2 rp_n, rg_n0, rg_n1, rg_n2, rg_n3;
    rp_n  = rec[min(pq, total-1)];
    rg_n0 = rec[min(gq+0, total-1)];
    rg_n1 = rec[min(gq+1, total-1)];
    rg_n2 = rec[min(gq+2, total-1)];
    rg_n3 = rec[min(gq+3, total-1)];

    for (int step = 0; step < nstep; ++step) {
        const int2 rp = rp_n;
        int sg[4], dg[4];
        sg[0] = rg_n0.x; dg[0] = rg_n0.y;
        sg[1] = rg_n1.x; dg[1] = rg_n1.y;
        sg[2] = rg_n2.x; dg[2] = rg_n2.y;
        sg[3] = rg_n3.x; dg[3] = rg_n3.y;
        int actm = 0;
        #pragma unroll
        for (int r = 0; r < 4; ++r)
            if (gq + step*4 + r < total) actm |= (1 << r);

        float q0 = pos[(size_t)rp.y*3+0] - pos[(size_t)rp.x*3+0];
        float q1 = pos[(size_t)rp.y*3+1] - pos[(size_t)rp.x*3+1];
        float q2 = pos[(size_t)rp.y*3+2] - pos[(size_t)rp.x*3+2];

        // ---- bf16 ushort4 gathers ----
        float gd[4][4], gxv[4][4];
        #pragma unroll
        for (int r = 0; r < 4; ++r) {
            const ushort4 a4 = *(const ushort4*)&ADb[(size_t)dg[r]*CC + lm*4];
            const ushort4 s4 = *(const ushort4*)&ASb[(size_t)sg[r]*CC + lm*4];
            const ushort4 x4 = *(const ushort4*)&xvb[(size_t)sg[r]*CC + lm*4];
            gd[r][0] = b2f(a4.x) - b2f(s4.x);
            gd[r][1] = b2f(a4.y) - b2f(s4.y);
            gd[r][2] = b2f(a4.z) - b2f(s4.z);
            gd[r][3] = b2f(a4.w) - b2f(s4.w);
            gxv[r][0] = b2f(x4.x); gxv[r][1] = b2f(x4.y);
            gxv[r][2] = b2f(x4.z); gxv[r][3] = b2f(x4.w);
        }

        if (step + 1 < nstep) {
            const int pn = pq + (step+1)*4;
            const int gn = gq + (step+1)*4;
            rp_n  = rec[min(pn,   total-1)];
            rg_n0 = rec[min(gn+0, total-1)];
            rg_n1 = rec[min(gn+1, total-1)];
            rg_n2 = rec[min(gn+2, total-1)];
            rg_n3 = rec[min(gn+3, total-1)];
        }

        // ---- p1 = relu(pdiff@pW1 + pb1) in A-frag layout ----
        s16x8 Alo, Ahi;
        #pragma unroll
        for (int j = 0; j < 16; ++j) {
            int k = lg*8 + (j & 7) + 32*(j >> 3);
            unsigned wa = ((volatile unsigned*)spw[0])[k];
            unsigned wb = ((volatile unsigned*)spw[1])[k];
            float w0 = __uint_as_float(wa << 16);
            float w1 = __uint_as_float(wa & 0xFFFF0000u);
            float w2 = __uint_as_float(wb << 16);
            float bb = __uint_as_float(wb & 0xFFFF0000u);
            float v = fmaxf(fmaf(q0, w0, fmaf(q1, w1, fmaf(q2, w2, bb))), 0.f);
            short b = (short)f2b(v);
            if (j < 8) Alo[j] = b; else Ahi[j-8] = b;
        }

        // ---- layer 1: delta = relu(p1 @ pW2 + pb2) ----
        f32x4 dlt[4];
        #pragma unroll
        for (int tt = 0; tt < 4; ++tt) {
            s16x8 b0 = *(const s16x8*)&swt[0][(lm + 16*tt)*72 + lg*8];
            s16x8 b1 = *(const s16x8*)&swt[0][(lm + 16*tt)*72 + 32 + lg*8];
            f32x4 z = {0.f, 0.f, 0.f, 0.f};
            z = __builtin_amdgcn_mfma_f32_16x16x32_bf16(Alo, b0, z, 0, 0, 0);
            z = __builtin_amdgcn_mfma_f32_16x16x32_bf16(Ahi, b1, z, 0, 0, 0);
            #pragma unroll
            for (int r = 0; r < 4; ++r) dlt[tt][r] = fmaxf(z[r] + pb2v[tt], 0.f);
        }

        // ---- transpose 1 ----
        #pragma unroll
        for (int tt = 0; tt < 4; ++tt)
            #pragma unroll
            for (int r = 0; r < 4; ++r)
                tbw[(lg*4+r)*72 + lm + 16*tt] = f2b(dlt[tt][r]);
        __builtin_amdgcn_wave_barrier();
        s16x8 Dlo = *(const s16x8*)&tbw[lm*72 + lg*8];
        s16x8 Dhi = *(const s16x8*)&tbw[lm*72 + 32 + lg*8];
        __builtin_amdgcn_wave_barrier();

        // ---- layer 2: h1 = relu(gd + delta@aW1 + ab1) -> transpose 2 ----
        #pragma unroll
        for (int tt = 0; tt < 4; ++tt) {
            s16x8 b0 = *(const s16x8*)&swt[1][(lm + 16*tt)*72 + lg*8];
            s16x8 b1 = *(const s16x8*)&swt[1][(lm + 16*tt)*72 + 32 + lg*8];
            f32x4 z = {0.f, 0.f, 0.f, 0.f};
            z = __builtin_amdgcn_mfma_f32_16x16x32_bf16(Dlo, b0, z, 0, 0, 0);
            z = __builtin_amdgcn_mfma_f32_16x16x32_bf16(Dhi, b1, z, 0, 0, 0);
            #pragma unroll
            for (int r = 0; r < 4; ++r) {
                float v = fmaxf(z[r] + gd[r][tt] + ab1v[tt], 0.f);
                tbw[(lg*4+r)*72 + lm + 16*tt] = f2b(v);
            }
        }
        __builtin_amdgcn_wave_barrier();
        s16x8 Hlo = *(const s16x8*)&tbw[lm*72 + lg*8];
        s16x8 Hhi = *(const s16x8*)&tbw[lm*72 + 32 + lg*8];
        __builtin_amdgcn_wave_barrier();

        // ---- layer 3: all 4 MFMA pairs first, then run logic per edge r ----
        f32x4 zz[4];
        #pragma unroll
        for (int tt = 0; tt < 4; ++tt) {
            s16x8 b0 = *(const s16x8*)&swt[2][(lm + 16*tt)*72 + lg*8];
            s16x8 b1 = *(const s16x8*)&swt[2][(lm + 16*tt)*72 + 32 + lg*8];
            f32x4 z = {0.f, 0.f, 0.f, 0.f};
            z = __builtin_amdgcn_mfma_f32_16x16x32_bf16(Hlo, b0, z, 0, 0, 0);
            zz[tt] = __builtin_amdgcn_mfma_f32_16x16x32_bf16(Hhi, b1, z, 0, 0, 0);
        }

        #pragma unroll
        for (int r = 0; r < 4; ++r) {
            if (!(actm & (1 << r))) continue;
            if (dg[r] != curD) {
                if (curD >= 0) {
                    if (firstF) {               // may be shared with predecessor quarter
                        #pragma unroll
                        for (int tt = 0; tt < 4; ++tt) {
                            size_t off = (size_t)curD*CC + lm + 16*tt;
                            atomicAdd(&esum[off], sA[tt]);
                            atomicMax(&outb[off], fmono(mxA[tt]));
                        }
                    } else {                    // interior run: exclusive -> plain store
                        #pragma unroll
                        for (int tt = 0; tt < 4; ++tt) {
                            size_t off = (size_t)curD*CC + lm + 16*tt;
                            esum[off] = sA[tt];
                            outb[off] = fmono(mxA[tt]);
                        }
                    }
                    firstF = false;
                }
                curD = dg[r];
                #pragma unroll
                for (int tt = 0; tt < 4; ++tt) { sA[tt] = 0.f; mxA[tt] = -INFINITY; }
            }
            #pragma unroll
            for (int tt = 0; tt < 4; ++tt) {
                float a  = fmaxf(zz[tt][r] + ab2v[tt], 0.f);
                float ee = __expf(a);
                float m  = ee * (gxv[r][tt] + dlt[tt][r]);
                sA[tt] += ee;
                mxA[tt] = fmaxf(mxA[tt], m);
            }
        }
    }

    // ---- epilogue: final run may extend into successor quarter -> atomics ----
    if (curD >= 0) {
        #pragma unroll
        for (int tt = 0; tt < 4; ++tt) {
            size_t off = (size_t)curD*CC + lm + 16*tt;
            atomicAdd(&esum[off], sA[tt]);
            atomicMax(&outb[off], fmono(mxA[tt]));
        }
    }
}

// ---- output kernel -----------------------------------------------------------------------
__global__ __launch_bounds__(256, 2) void out_kernel(
    const unsigned* outb_in,            // aliases out -- no restrict
    const float* __restrict__ esum,
    const float* __restrict__ W_out, const float* __restrict__ b_out,
    float* out, int N)
{
    __shared__ float vt[64][68];
    const int t = threadIdx.x, lane = t & 63, quad = t >> 6;
    const int n0 = blockIdx.x * 64;
    float wreg[64];
    #pragma unroll
    for (int k4 = 0; k4 < 16; ++k4)
        *(float4*)&wreg[k4*4] = *(const float4*)&W_out[(size_t)lane*CC + k4*4];
    #pragma unroll 4
    for (int i = 0; i < 16; ++i) {
        int r = i*4 + quad, n = n0 + r;
        float v = 0.f;
        if (n < N) {
            unsigned u = outb_in[(size_t)n*CC + lane];
            u = (u >> 31) ? (u ^ 0x80000000u) : ~u;   // inverse of fmono
            v = __uint_as_float(u) / esum[(size_t)n*CC + lane];
        }
        vt[r][lane] = v;
    }
    __syncthreads();
    const float bo = b_out[lane];
    #pragma unroll 2
    for (int i = 0; i < 16; ++i) {
        int r = i*4 + quad, n = n0 + r;
        if (n >= N) continue;
        float acc = bo;
        #pragma unroll
        for (int k4 = 0; k4 < 16; ++k4) {
            float4 xx = *(const float4*)&vt[r][k4*4];
            acc += xx.x*wreg[k4*4+0] + xx.y*wreg[k4*4+1]
                 + xx.z*wreg[k4*4+2] + xx.w*wreg[k4*4+3];
        }
        out[(size_t)n*CC + lane] = fmaxf(acc, 0.f);
    }
}

extern "C" void kernel_launch(void* const* d_in, const int* in_sizes, int n_in,
                              void* d_out, int out_size, void* d_ws, size_t ws_size,
                              hipStream_t stream)
{
    const float* x     = (const float*)d_in[0];
    const float* pos   = (const float*)d_in[1];
    const int*   ei    = (const int*)d_in[2];
    const float* W_in  = (const float*)d_in[3];
    const float* b_in  = (const float*)d_in[4];
    const float* W_out = (const float*)d_in[5];
    const float* b_out = (const float*)d_in[6];
    const float* W_lin = (const float*)d_in[7];
    const float* W_src = (const float*)d_in[8];
    const float* W_dst = (const float*)d_in[9];
    const float* pW1   = (const float*)d_in[10];
    const float* pb1   = (const float*)d_in[11];
    const float* pW2   = (const float*)d_in[12];
    const float* pb2   = (const float*)d_in[13];
    const float* aW1   = (const float*)d_in[14];
    const float* ab1   = (const float*)d_in[15];
    const float* aW2   = (const float*)d_in[16];
    const float* ab2   = (const float*)d_in[17];

    const int N = in_sizes[0] / CC;
    const int E = in_sizes[2] / 2;
    const size_t nc = (size_t)N * CC;

    char* wsb = (char*)d_ws;
    unsigned short* ASb = (unsigned short*)wsb;        // nc * 2B
    unsigned short* ADb = ASb + nc;                    // nc * 2B
    unsigned short* xvb = ADb + nc;                    // nc * 2B
    float* esum = (float*)(((size_t)(xvb + nc) + 15) & ~(size_t)15);   // nc * 4B
    unsigned* cnt       = (unsigned*)(esum + nc);
    unsigned* chunk_off = cnt + N;
    unsigned* cursor    = chunk_off + N;
    unsigned* partials  = cursor + N;                  // 1024 entries
    size_t rec_off = ((size_t)((char*)(partials + 1024) - wsb) + 15) & ~(size_t)15;
    int2* rec = (int2*)(wsb + rec_off);
    unsigned* outb = (unsigned*)d_out;

    hipMemsetAsync(esum, 0, nc*sizeof(float), stream);
    hipMemsetAsync(outb, 0, nc*sizeof(float), stream);
    hipMemsetAsync(cnt, 0, (size_t)N*sizeof(unsigned), stream);

    const int nblk = (N + 63) / 64;
    node_proj_kernel<<<nblk, 256, 0, stream>>>(x, W_in, b_in, W_src, W_dst, W_lin, aW1,
                                               ASb, ADb, xvb, ei, cnt, N, E);
    const int nchunks = (N + 1023) / 1024;
    scan1_kernel<<<nchunks, SCAN_T, 0, stream>>>(cnt, chunk_off, partials, N);
    scan2_kernel<<<1, 1024, 0, stream>>>(partials, nchunks);
    scan3_kernel<<<(N + 255)/256, 256, 0, stream>>>(chunk_off, partials, cursor, N);
    scatter_kernel<<<2048, 256, 0, stream>>>(ei, cursor, rec, N, E);
    edge_mfma_kernel<<<2048, 256, 0, stream>>>(rec, pos, ADb, ASb, xvb,
                                               pW1, pb1, pW2, pb2, aW1, ab1, aW2, ab2,
                                               esum, outb, N, E);
    out_kernel<<<nblk, 256, 0, stream>>>(outb, esum, W_out, b_out, (float*)d_out, N);
}

// Round 17
// 498.521 us; speedup vs baseline: 3.6661x; 1.3231x over previous
//
#include <hip/hip_runtime.h>
#include <hip/hip_bf16.h>

#define CC 64

typedef __attribute__((ext_vector_type(8))) short s16x8;
typedef __attribute__((ext_vector_type(4))) float f32x4;

__device__ __forceinline__ unsigned short f2b(float f) {   // f32 -> bf16 bits, RNE
    unsigned u = __float_as_uint(f);
    u += 0x7FFF + ((u >> 16) & 1);
    return (unsigned short)(u >> 16);
}
__device__ __forceinline__ float b2f(unsigned short b) {   // bf16 bits -> f32
    return __uint_as_float((unsigned)b << 16);
}
__device__ __forceinline__ unsigned fmono(float f) {       // order-preserving f32->u32
    unsigned u = __float_as_uint(f);
    return u ^ ((unsigned)((int)u >> 31) | 0x80000000u);
}

// ---- node kernel (MFMA): h=relu(x@W_in^T+b); AS=(h@W_src^T)@aW1; AD=(h@W_dst^T)@aW1;
// xv=h@W_lin^T. All outputs bf16, permuted layout (channel c -> column (c&15)*4+(c>>4)).
// Per wave: 16 nodes. Weights staged in LDS as bf16 B-fragments.
__global__ __launch_bounds__(256, 2) void node_mfma_kernel(
    const float* __restrict__ x,
    const float* __restrict__ W_in, const float* __restrict__ b_in,
    const float* __restrict__ W_src, const float* __restrict__ W_dst,
    const float* __restrict__ W_lin, const float* __restrict__ aW1,
    unsigned short* __restrict__ ASb, unsigned short* __restrict__ ADb,
    unsigned short* __restrict__ xvb,
    const int* __restrict__ ei, unsigned* __restrict__ cnt, int N, int E)
{
    const int tid = threadIdx.x;
    const int lane = tid & 63;
    const int wid  = tid >> 6;
    const int lm = lane & 15;
    const int lg = lane >> 4;

    __shared__ __align__(16) unsigned short swt[5][64 * 72];  // W_in,W_src,W_dst,W_lin,[aW1]
    __shared__ __align__(16) unsigned short tb[4][16 * 72];

    {   // stage weights: rows 0-3 are [out][in] row-major; aW1 is [in][out] -> column copy
        const float* Wr[4] = {W_in, W_src, W_dst, W_lin};
        #pragma unroll
        for (int w = 0; w < 4; ++w)
            for (int idx = tid; idx < 4096; idx += 256) {
                int o = idx >> 6, k = idx & 63;
                swt[w][o*72 + k] = f2b(Wr[w][(size_t)o*64 + k]);
            }
        for (int idx = tid; idx < 4096; idx += 256) {
            int k = idx >> 6, o = idx & 63;
            swt[4][o*72 + k] = f2b(aW1[idx]);     // aW1[k][o]
        }
    }
    __syncthreads();

    const int wbase = blockIdx.x * 64 + wid * 16;
    unsigned short* tbw = tb[wid];

    if (wbase < N) {
        float bin[4];
        #pragma unroll
        for (int tt = 0; tt < 4; ++tt) bin[tt] = b_in[lm + 16*tt];

        // ---- load x into A-frags (row = node wbase+lm, k per edge-kernel convention) ----
        const int xrow = min(wbase + lm, N-1);
        const float* xp = &x[(size_t)xrow*CC];
        float4 a0 = *(const float4*)&xp[lg*8];
        float4 a1 = *(const float4*)&xp[lg*8 + 4];
        float4 a2 = *(const float4*)&xp[32 + lg*8];
        float4 a3 = *(const float4*)&xp[32 + lg*8 + 4];
        s16x8 Xlo, Xhi;
        Xlo[0]=(short)f2b(a0.x); Xlo[1]=(short)f2b(a0.y); Xlo[2]=(short)f2b(a0.z); Xlo[3]=(short)f2b(a0.w);
        Xlo[4]=(short)f2b(a1.x); Xlo[5]=(short)f2b(a1.y); Xlo[6]=(short)f2b(a1.z); Xlo[7]=(short)f2b(a1.w);
        Xhi[0]=(short)f2b(a2.x); Xhi[1]=(short)f2b(a2.y); Xhi[2]=(short)f2b(a2.z); Xhi[3]=(short)f2b(a2.w);
        Xhi[4]=(short)f2b(a3.x); Xhi[5]=(short)f2b(a3.y); Xhi[6]=(short)f2b(a3.z); Xhi[7]=(short)f2b(a3.w);

        // helpers
        auto mm = [&](s16x8 alo, s16x8 ahi, int w, f32x4* zz) {
            #pragma unroll
            for (int tt = 0; tt < 4; ++tt) {
                s16x8 b0 = *(const s16x8*)&swt[w][(lm + 16*tt)*72 + lg*8];
                s16x8 b1 = *(const s16x8*)&swt[w][(lm + 16*tt)*72 + 32 + lg*8];
                f32x4 z = {0.f, 0.f, 0.f, 0.f};
                z = __builtin_amdgcn_mfma_f32_16x16x32_bf16(alo, b0, z, 0, 0, 0);
                zz[tt] = __builtin_amdgcn_mfma_f32_16x16x32_bf16(ahi, b1, z, 0, 0, 0);
            }
        };
        auto transpose = [&](const f32x4* zz, s16x8& olo, s16x8& ohi) {
            #pragma unroll
            for (int tt = 0; tt < 4; ++tt)
                #pragma unroll
                for (int r = 0; r < 4; ++r)
                    tbw[(lg*4+r)*72 + lm + 16*tt] = f2b(zz[tt][r]);
            __builtin_amdgcn_wave_barrier();
            olo = *(const s16x8*)&tbw[lm*72 + lg*8];
            ohi = *(const s16x8*)&tbw[lm*72 + 32 + lg*8];
            __builtin_amdgcn_wave_barrier();
        };
        auto store_perm = [&](const f32x4* zz, unsigned short* out) {
            #pragma unroll
            for (int r = 0; r < 4; ++r) {
                int n = wbase + lg*4 + r;
                if (n < N) {
                    ushort4 v = make_ushort4(f2b(zz[0][r]), f2b(zz[1][r]),
                                             f2b(zz[2][r]), f2b(zz[3][r]));
                    *(ushort4*)&out[(size_t)n*CC + lm*4] = v;
                }
            }
        };

        f32x4 zh[4], zt[4], zo[4];
        // h = relu(x @ W_in^T + b_in)
        mm(Xlo, Xhi, 0, zh);
        #pragma unroll
        for (int tt = 0; tt < 4; ++tt)
            #pragma unroll
            for (int r = 0; r < 4; ++r)
                zh[tt][r] = fmaxf(zh[tt][r] + bin[tt], 0.f);
        s16x8 Hlo, Hhi;
        transpose(zh, Hlo, Hhi);

        // AS = (h @ W_src^T) @ aW1
        mm(Hlo, Hhi, 1, zt);
        { s16x8 Tlo, Thi; transpose(zt, Tlo, Thi); mm(Tlo, Thi, 4, zo); }
        store_perm(zo, ASb);

        // AD = (h @ W_dst^T) @ aW1
        mm(Hlo, Hhi, 2, zt);
        { s16x8 Tlo, Thi; transpose(zt, Tlo, Thi); mm(Tlo, Thi, 4, zo); }
        store_perm(zo, ADb);

        // xv = h @ W_lin^T
        mm(Hlo, Hhi, 3, zo);
        store_perm(zo, xvb);
    }

    // fused dst histogram
    const int total = E + N;
    for (int e = blockIdx.x*256 + tid; e < total; e += gridDim.x*256) {
        int d = (e < E) ? min(max(ei[(size_t)E + e], 0), N-1) : (e - E);
        atomicAdd(&cnt[d], 1u);
    }
}

// ---- exclusive scan (3 kernels) + scatter ------------------------------------------------
#define SCAN_T 256
__global__ __launch_bounds__(SCAN_T) void scan1_kernel(
    const unsigned* __restrict__ cnt, unsigned* __restrict__ chunk_off,
    unsigned* __restrict__ partials, int n)
{
    __shared__ unsigned sh[SCAN_T];
    const int t = threadIdx.x, b0 = blockIdx.x * (SCAN_T*4);
    unsigned v[4], s = 0;
    #pragma unroll
    for (int i = 0; i < 4; ++i) {
        int idx = b0 + t*4 + i;
        v[i] = (idx < n) ? cnt[idx] : 0u;
        s += v[i];
    }
    sh[t] = s; __syncthreads();
    for (int d = 1; d < SCAN_T; d <<= 1) {
        unsigned xv = (t >= d) ? sh[t-d] : 0u;
        __syncthreads();
        sh[t] += xv;
        __syncthreads();
    }
    unsigned run = (t > 0) ? sh[t-1] : 0u;
    #pragma unroll
    for (int i = 0; i < 4; ++i) {
        int idx = b0 + t*4 + i;
        if (idx < n) chunk_off[idx] = run;
        run += v[i];
    }
    if (t == SCAN_T-1) partials[blockIdx.x] = sh[SCAN_T-1];
}

__global__ __launch_bounds__(1024) void scan2_kernel(unsigned* __restrict__ partials, int nb)
{
    __shared__ unsigned sh[1024];
    const int t = threadIdx.x;
    sh[t] = (t < nb) ? partials[t] : 0u; __syncthreads();
    for (int d = 1; d < 1024; d <<= 1) {
        unsigned xv = (t >= d) ? sh[t-d] : 0u;
        __syncthreads();
        sh[t] += xv;
        __syncthreads();
    }
    if (t < nb) partials[t] = (t > 0) ? sh[t-1] : 0u;
}

__global__ __launch_bounds__(256) void scan3_kernel(
    const unsigned* __restrict__ chunk_off, const unsigned* __restrict__ partials,
    unsigned* __restrict__ cursor, int n)
{
    int i = blockIdx.x*256 + threadIdx.x;
    if (i < n) cursor[i] = chunk_off[i] + partials[i >> 10];
}

__global__ __launch_bounds__(256) void scatter_kernel(
    const int* __restrict__ ei, unsigned* __restrict__ cursor,
    int2* __restrict__ rec, int N, int E)
{
    const int total = E + N;
    for (int e = blockIdx.x*256 + threadIdx.x; e < total; e += gridDim.x*256) {
        int s, d;
        if (e < E) {
            s = min(max(ei[e], 0), N-1);
            d = min(max(ei[(size_t)E + e], 0), N-1);
        } else { s = d = e - E; }
        unsigned p = atomicAdd(&cursor[d], 1u);
        rec[p] = make_int2(s, d);
    }
}

// ---- edge kernel: contiguous per-lg quarters; interior runs -> PLAIN stores --------------
__global__ __launch_bounds__(256, 3) void edge_mfma_kernel(
    const int2* __restrict__ rec, const float* __restrict__ pos,
    const unsigned short* __restrict__ ADb, const unsigned short* __restrict__ ASb,
    const unsigned short* __restrict__ xvb,
    const float* __restrict__ pW1, const float* __restrict__ pb1,
    const float* __restrict__ pW2, const float* __restrict__ pb2,
    const float* __restrict__ aW1, const float* __restrict__ ab1,
    const float* __restrict__ aW2, const float* __restrict__ ab2,
    float* __restrict__ esum, unsigned* __restrict__ outb,
    int N, int E)
{
    const int tid = threadIdx.x;
    const int lane = tid & 63;
    const int wid  = tid >> 6;
    const int lm = lane & 15;
    const int lg = lane >> 4;

    __shared__ __align__(16) unsigned short swt[3][64 * 72];
    __shared__ __align__(16) unsigned short tb[4][16 * 72];
    __shared__ unsigned spw[2][64];

    {
        const float* Wsrc[3] = {pW2, aW1, aW2};
        #pragma unroll
        for (int w = 0; w < 3; ++w)
            for (int idx = tid; idx < 4096; idx += 256) {
                int k = idx >> 6, o = idx & 63;
                swt[w][o*72 + k] = f2b(Wsrc[w][idx]);
            }
        if (tid < 64) {
            spw[0][tid] = (unsigned)f2b(pW1[tid])     | ((unsigned)f2b(pW1[64+tid]) << 16);
            spw[1][tid] = (unsigned)f2b(pW1[128+tid]) | ((unsigned)f2b(pb1[tid])    << 16);
        }
    }
    __syncthreads();

    float pb2v[4], ab1v[4], ab2v[4];
    #pragma unroll
    for (int tt = 0; tt < 4; ++tt) {
        pb2v[tt] = pb2[lm + 16*tt];
        ab1v[tt] = ab1[lm + 16*tt];
        ab2v[tt] = ab2[lm + 16*tt];
    }

    unsigned short* tbw = tb[wid];
    const int total = E + N;
    const int ntiles = (total + 15) >> 4;
    const int nwaves = gridDim.x * 4;
    const int tpw = (ntiles + nwaves - 1) / nwaves;
    const int gw = blockIdx.x * 4 + wid;
    const int t0 = min(gw * tpw, ntiles);
    const int t1 = min(t0 + tpw, ntiles);
    if (t0 >= t1) return;
    const int nstep = t1 - t0;
    const int qlen  = 4 * nstep;
    const int rbase = t0 << 4;
    const int pq = rbase + (lm >> 2)*qlen + (lm & 3);
    const int gq = rbase + lg*qlen;

    int   curD = -1;
    bool  firstF = true;
    float sA[4]  = {0.f, 0.f, 0.f, 0.f};
    float mxA[4] = {-INFINITY, -INFINITY, -INFINITY, -INFINITY};

    int2 rp_n, rg_n0, rg_n1, rg_n2, rg_n3;
    rp_n  = rec[min(pq, total-1)];
    rg_n0 = rec[min(gq+0, total-1)];
    rg_n1 = rec[min(gq+1, total-1)];
    rg_n2 = rec[min(gq+2, total-1)];
    rg_n3 = rec[min(gq+3, total-1)];

    for (int step = 0; step < nstep; ++step) {
        const int2 rp = rp_n;
        int sg[4], dg[4];
        sg[0] = rg_n0.x; dg[0] = rg_n0.y;
        sg[1] = rg_n1.x; dg[1] = rg_n1.y;
        sg[2] = rg_n2.x; dg[2] = rg_n2.y;
        sg[3] = rg_n3.x; dg[3] = rg_n3.y;
        int actm = 0;
        #pragma unroll
        for (int r = 0; r < 4; ++r)
            if (gq + step*4 + r < total) actm |= (1 << r);

        float q0 = pos[(size_t)rp.y*3+0] - pos[(size_t)rp.x*3+0];
        float q1 = pos[(size_t)rp.y*3+1] - pos[(size_t)rp.x*3+1];
        float q2 = pos[(size_t)rp.y*3+2] - pos[(size_t)rp.x*3+2];

        float gd[4][4], gxv[4][4];
        #pragma unroll
        for (int r = 0; r < 4; ++r) {
            const ushort4 a4 = *(const ushort4*)&ADb[(size_t)dg[r]*CC + lm*4];
            const ushort4 s4 = *(const ushort4*)&ASb[(size_t)sg[r]*CC + lm*4];
            const ushort4 x4 = *(const ushort4*)&xvb[(size_t)sg[r]*CC + lm*4];
            gd[r][0] = b2f(a4.x) - b2f(s4.x);
            gd[r][1] = b2f(a4.y) - b2f(s4.y);
            gd[r][2] = b2f(a4.z) - b2f(s4.z);
            gd[r][3] = b2f(a4.w) - b2f(s4.w);
            gxv[r][0] = b2f(x4.x); gxv[r][1] = b2f(x4.y);
            gxv[r][2] = b2f(x4.z); gxv[r][3] = b2f(x4.w);
        }

        if (step + 1 < nstep) {
            const int pn = pq + (step+1)*4;
            const int gn = gq + (step+1)*4;
            rp_n  = rec[min(pn,   total-1)];
            rg_n0 = rec[min(gn+0, total-1)];
            rg_n1 = rec[min(gn+1, total-1)];
            rg_n2 = rec[min(gn+2, total-1)];
            rg_n3 = rec[min(gn+3, total-1)];
        }

        s16x8 Alo, Ahi;
        #pragma unroll
        for (int j = 0; j < 16; ++j) {
            int k = lg*8 + (j & 7) + 32*(j >> 3);
            unsigned wa = ((volatile unsigned*)spw[0])[k];
            unsigned wb = ((volatile unsigned*)spw[1])[k];
            float w0 = __uint_as_float(wa << 16);
            float w1 = __uint_as_float(wa & 0xFFFF0000u);
            float w2 = __uint_as_float(wb << 16);
            float bb = __uint_as_float(wb & 0xFFFF0000u);
            float v = fmaxf(fmaf(q0, w0, fmaf(q1, w1, fmaf(q2, w2, bb))), 0.f);
            short b = (short)f2b(v);
            if (j < 8) Alo[j] = b; else Ahi[j-8] = b;
        }

        f32x4 dlt[4];
        #pragma unroll
        for (int tt = 0; tt < 4; ++tt) {
            s16x8 b0 = *(const s16x8*)&swt[0][(lm + 16*tt)*72 + lg*8];
            s16x8 b1 = *(const s16x8*)&swt[0][(lm + 16*tt)*72 + 32 + lg*8];
            f32x4 z = {0.f, 0.f, 0.f, 0.f};
            z = __builtin_amdgcn_mfma_f32_16x16x32_bf16(Alo, b0, z, 0, 0, 0);
            z = __builtin_amdgcn_mfma_f32_16x16x32_bf16(Ahi, b1, z, 0, 0, 0);
            #pragma unroll
            for (int r = 0; r < 4; ++r) dlt[tt][r] = fmaxf(z[r] + pb2v[tt], 0.f);
        }

        #pragma unroll
        for (int tt = 0; tt < 4; ++tt)
            #pragma unroll
            for (int r = 0; r < 4; ++r)
                tbw[(lg*4+r)*72 + lm + 16*tt] = f2b(dlt[tt][r]);
        __builtin_amdgcn_wave_barrier();
        s16x8 Dlo = *(const s16x8*)&tbw[lm*72 + lg*8];
        s16x8 Dhi = *(const s16x8*)&tbw[lm*72 + 32 + lg*8];
        __builtin_amdgcn_wave_barrier();

        #pragma unroll
        for (int tt = 0; tt < 4; ++tt) {
            s16x8 b0 = *(const s16x8*)&swt[1][(lm + 16*tt)*72 + lg*8];
            s16x8 b1 = *(const s16x8*)&swt[1][(lm + 16*tt)*72 + 32 + lg*8];
            f32x4 z = {0.f, 0.f, 0.f, 0.f};
            z = __builtin_amdgcn_mfma_f32_16x16x32_bf16(Dlo, b0, z, 0, 0, 0);
            z = __builtin_amdgcn_mfma_f32_16x16x32_bf16(Dhi, b1, z, 0, 0, 0);
            #pragma unroll
            for (int r = 0; r < 4; ++r) {
                float v = fmaxf(z[r] + gd[r][tt] + ab1v[tt], 0.f);
                tbw[(lg*4+r)*72 + lm + 16*tt] = f2b(v);
            }
        }
        __builtin_amdgcn_wave_barrier();
        s16x8 Hlo = *(const s16x8*)&tbw[lm*72 + lg*8];
        s16x8 Hhi = *(const s16x8*)&tbw[lm*72 + 32 + lg*8];
        __builtin_amdgcn_wave_barrier();

        f32x4 zz[4];
        #pragma unroll
        for (int tt = 0; tt < 4; ++tt) {
            s16x8 b0 = *(const s16x8*)&swt[2][(lm + 16*tt)*72 + lg*8];
            s16x8 b1 = *(const s16x8*)&swt[2][(lm + 16*tt)*72 + 32 + lg*8];
            f32x4 z = {0.f, 0.f, 0.f, 0.f};
            z = __builtin_amdgcn_mfma_f32_16x16x32_bf16(Hlo, b0, z, 0, 0, 0);
            zz[tt] = __builtin_amdgcn_mfma_f32_16x16x32_bf16(Hhi, b1, z, 0, 0, 0);
        }

        #pragma unroll
        for (int r = 0; r < 4; ++r) {
            if (!(actm & (1 << r))) continue;
            if (dg[r] != curD) {
                if (curD >= 0) {
                    if (firstF) {
                        #pragma unroll
                        for (int tt = 0; tt < 4; ++tt) {
                            size_t off = (size_t)curD*CC + lm + 16*tt;
                            atomicAdd(&esum[off], sA[tt]);
                            atomicMax(&outb[off], fmono(mxA[tt]));
                        }
                    } else {
                        #pragma unroll
                        for (int tt = 0; tt < 4; ++tt) {
                            size_t off = (size_t)curD*CC + lm + 16*tt;
                            esum[off] = sA[tt];
                            outb[off] = fmono(mxA[tt]);
                        }
                    }
                    firstF = false;
                }
                curD = dg[r];
                #pragma unroll
                for (int tt = 0; tt < 4; ++tt) { sA[tt] = 0.f; mxA[tt] = -INFINITY; }
            }
            #pragma unroll
            for (int tt = 0; tt < 4; ++tt) {
                float a  = fmaxf(zz[tt][r] + ab2v[tt], 0.f);
                float ee = __expf(a);
                float m  = ee * (gxv[r][tt] + dlt[tt][r]);
                sA[tt] += ee;
                mxA[tt] = fmaxf(mxA[tt], m);
            }
        }
    }

    if (curD >= 0) {
        #pragma unroll
        for (int tt = 0; tt < 4; ++tt) {
            size_t off = (size_t)curD*CC + lm + 16*tt;
            atomicAdd(&esum[off], sA[tt]);
            atomicMax(&outb[off], fmono(mxA[tt]));
        }
    }
}

// ---- output kernel -----------------------------------------------------------------------
__global__ __launch_bounds__(256, 2) void out_kernel(
    const unsigned* outb_in,            // aliases out -- no restrict
    const float* __restrict__ esum,
    const float* __restrict__ W_out, const float* __restrict__ b_out,
    float* out, int N)
{
    __shared__ float vt[64][68];
    const int t = threadIdx.x, lane = t & 63, quad = t >> 6;
    const int n0 = blockIdx.x * 64;
    float wreg[64];
    #pragma unroll
    for (int k4 = 0; k4 < 16; ++k4)
        *(float4*)&wreg[k4*4] = *(const float4*)&W_out[(size_t)lane*CC + k4*4];
    #pragma unroll 4
    for (int i = 0; i < 16; ++i) {
        int r = i*4 + quad, n = n0 + r;
        float v = 0.f;
        if (n < N) {
            unsigned u = outb_in[(size_t)n*CC + lane];
            u = (u >> 31) ? (u ^ 0x80000000u) : ~u;   // inverse of fmono
            v = __uint_as_float(u) / esum[(size_t)n*CC + lane];
        }
        vt[r][lane] = v;
    }
    __syncthreads();
    const float bo = b_out[lane];
    #pragma unroll 2
    for (int i = 0; i < 16; ++i) {
        int r = i*4 + quad, n = n0 + r;
        if (n >= N) continue;
        float acc = bo;
        #pragma unroll
        for (int k4 = 0; k4 < 16; ++k4) {
            float4 xx = *(const float4*)&vt[r][k4*4];
            acc += xx.x*wreg[k4*4+0] + xx.y*wreg[k4*4+1]
                 + xx.z*wreg[k4*4+2] + xx.w*wreg[k4*4+3];
        }
        out[(size_t)n*CC + lane] = fmaxf(acc, 0.f);
    }
}

extern "C" void kernel_launch(void* const* d_in, const int* in_sizes, int n_in,
                              void* d_out, int out_size, void* d_ws, size_t ws_size,
                              hipStream_t stream)
{
    const float* x     = (const float*)d_in[0];
    const float* pos   = (const float*)d_in[1];
    const int*   ei    = (const int*)d_in[2];
    const float* W_in  = (const float*)d_in[3];
    const float* b_in  = (const float*)d_in[4];
    const float* W_out = (const float*)d_in[5];
    const float* b_out = (const float*)d_in[6];
    const float* W_lin = (const float*)d_in[7];
    const float* W_src = (const float*)d_in[8];
    const float* W_dst = (const float*)d_in[9];
    const float* pW1   = (const float*)d_in[10];
    const float* pb1   = (const float*)d_in[11];
    const float* pW2   = (const float*)d_in[12];
    const float* pb2   = (const float*)d_in[13];
    const float* aW1   = (const float*)d_in[14];
    const float* ab1   = (const float*)d_in[15];
    const float* aW2   = (const float*)d_in[16];
    const float* ab2   = (const float*)d_in[17];

    const int N = in_sizes[0] / CC;
    const int E = in_sizes[2] / 2;
    const size_t nc = (size_t)N * CC;

    char* wsb = (char*)d_ws;
    unsigned short* ASb = (unsigned short*)wsb;        // nc * 2B
    unsigned short* ADb = ASb + nc;                    // nc * 2B
    unsigned short* xvb = ADb + nc;                    // nc * 2B
    float* esum = (float*)(((size_t)(xvb + nc) + 15) & ~(size_t)15);   // nc * 4B
    unsigned* cnt       = (unsigned*)(esum + nc);
    unsigned* chunk_off = cnt + N;
    unsigned* cursor    = chunk_off + N;
    unsigned* partials  = cursor + N;                  // 1024 entries
    size_t rec_off = ((size_t)((char*)(partials + 1024) - wsb) + 15) & ~(size_t)15;
    int2* rec = (int2*)(wsb + rec_off);
    unsigned* outb = (unsigned*)d_out;

    hipMemsetAsync(esum, 0, nc*sizeof(float), stream);
    hipMemsetAsync(outb, 0, nc*sizeof(float), stream);
    hipMemsetAsync(cnt, 0, (size_t)N*sizeof(unsigned), stream);

    const int nblk = (N + 63) / 64;
    node_mfma_kernel<<<nblk, 256, 0, stream>>>(x, W_in, b_in, W_src, W_dst, W_lin, aW1,
                                               ASb, ADb, xvb, ei, cnt, N, E);
    const int nchunks = (N + 1023) / 1024;
    scan1_kernel<<<nchunks, SCAN_T, 0, stream>>>(cnt, chunk_off, partials, N);
    scan2_kernel<<<1, 1024, 0, stream>>>(partials, nchunks);
    scan3_kernel<<<(N + 255)/256, 256, 0, stream>>>(chunk_off, partials, cursor, N);
    scatter_kernel<<<2048, 256, 0, stream>>>(ei, cursor, rec, N, E);
    edge_mfma_kernel<<<2048, 256, 0, stream>>>(rec, pos, ADb, ASb, xvb,
                                               pW1, pb1, pW2, pb2, aW1, ab1, aW2, ab2,
                                               esum, outb, N, E);
    out_kernel<<<nblk, 256, 0, stream>>>(outb, esum, W_out, b_out, (float*)d_out, N);
}